// Round 1
// baseline (132.453 us; speedup 1.0000x reference)
//
#include <hip/hip_runtime.h>
#include <hip/hip_bf16.h>
#include <math.h>

// CrossAttention3D: B=1, C=64, N=4096, 8 heads x hd=8.
// MFMA plan (32x32x16 bf16, fp32 accum):
//   QK:  D = A(K)xB(Q) = S^T tile [32k x 32q]; kslots 8-15 zeroed (exec-masked
//        load, upper half = 0).
//   softmax: no max subtraction (|logit| <~ 2.6 in base-2); p = exp2(s).
//   PV (transposed): out^T[d][q] = Vt(A) x P^T(B). P^T is built IN REGISTERS
//        from the QK output via v_cvt_pk_bf16_f32 + v_permlane32_swap_b32
//        (no LDS round trip at all). Vt row 8 = ones -> D row 8 = l (denom).
//   split-K over blockIdx.z; partials summed (no max -> linear combine).
// Precision: bf16 inputs / fp32 accumulate -> predicted absmax ~5e-6 (thr 2.47e-5).

#define N_VOX 4096
#define NH 8
#define QSCALE 0.51010813f  // 8^-0.5 * log2(e)

typedef unsigned short ushort_t;
typedef __attribute__((ext_vector_type(8))) short bf16x8;
typedef __attribute__((ext_vector_type(16))) float f32x16;

__device__ __forceinline__ unsigned short f2bf(float f) {
  union { float f; unsigned u; } v; v.f = f;
  unsigned r = v.u + 0x7FFFu + ((v.u >> 16) & 1u);
  return (unsigned short)(r >> 16);
}
__device__ __forceinline__ unsigned pk2bf(float a, float b) {
  __hip_bfloat162 h = __float22bfloat162_rn(float2{a, b});
  union { __hip_bfloat162 h; unsigned u; } c; c.h = h;
  return c.u;
}
__device__ __forceinline__ float ex2(float x) { return __builtin_amdgcn_exp2f(x); }

// v_permlane32_swap_b32: a[32..63] <-> b[0..31]. After the swap:
//   a' = lanes<32 keep a, lanes>=32 get b[lane-32]
//   b' = lanes<32 get a[lane+32], lanes>=32 keep b
__device__ __forceinline__ void plswap(unsigned& a, unsigned& b) {
  asm("v_permlane32_swap_b32 %0, %1" : "+v"(a), "+v"(b));
}

// ---------------------------------------------------------------------------
// Projections -> packed bf16 operand layouts.
// grid (16, 16) x 256: bx 0-7 = Q(dec) head; 8-15 = K+V(mae) head.
__global__ __launch_bounds__(256) void qkv_pack(
    const float* __restrict__ dec, const float* __restrict__ mae,
    const float* __restrict__ qw, const float* __restrict__ qb_,
    const float* __restrict__ kw, const float* __restrict__ kb,
    const float* __restrict__ vw, const float* __restrict__ vb,
    ushort_t* __restrict__ Qp, ushort_t* __restrict__ Kp,
    ushort_t* __restrict__ Vt) {
  const int bx = blockIdx.x;
  const int n = blockIdx.y * 256 + threadIdx.x;

  if (bx < 8) {
    const int h = bx;
    float x[64];
#pragma unroll
    for (int c = 0; c < 64; ++c) x[c] = dec[c * N_VOX + n];
    float qv[8];
#pragma unroll
    for (int j = 0; j < 8; ++j) {
      const int o = h * 8 + j;
      float a = qb_[o];
#pragma unroll
      for (int c = 0; c < 64; ++c) a = fmaf(x[c], qw[o * 64 + c], a);
      qv[j] = a * QSCALE;  // fold hd^-0.5 * log2(e) into Q
    }
    uint4 pk;
    pk.x = pk2bf(qv[0], qv[1]); pk.y = pk2bf(qv[2], qv[3]);
    pk.z = pk2bf(qv[4], qv[5]); pk.w = pk2bf(qv[6], qv[7]);
    *(uint4*)(Qp + ((size_t)h * N_VOX + n) * 8) = pk;
  } else {
    const int h = bx - 8;
    float x[64];
#pragma unroll
    for (int c = 0; c < 64; ++c) x[c] = mae[c * N_VOX + n];
    float kv[8], vv[8];
#pragma unroll
    for (int j = 0; j < 8; ++j) {
      const int o = h * 8 + j;
      float a = kb[o], b = vb[o];
#pragma unroll
      for (int c = 0; c < 64; ++c) {
        a = fmaf(x[c], kw[o * 64 + c], a);
        b = fmaf(x[c], vw[o * 64 + c], b);
      }
      kv[j] = a; vv[j] = b;
    }
    uint4 pk;
    pk.x = pk2bf(kv[0], kv[1]); pk.y = pk2bf(kv[2], kv[3]);
    pk.z = pk2bf(kv[4], kv[5]); pk.w = pk2bf(kv[6], kv[7]);
    *(uint4*)(Kp + ((size_t)h * N_VOX + n) * 8) = pk;
#pragma unroll
    for (int d = 0; d < 8; ++d)
      Vt[((size_t)(h * 32 + d)) * N_VOX + n] = f2bf(vv[d]);
    Vt[((size_t)(h * 32 + 8)) * N_VOX + n] = 0x3F80;  // ones row -> l
  }
}

// ---------------------------------------------------------------------------
// Per q-tile PV: build P^T B-frag in registers from QK output s, accumulate.
// s reg r (lane l): S~[key = kcur + (r&3)+8*(r>>2)+4*(l>>5)][q = l&31].
// For 16-key group g (regs g*8 .. g*8+7):
//   X0=pk(e0,e1) X1=pk(e2,e3) X2=pk(e4,e5) X3=pk(e6,e7)
//   swap(X0,X2) -> (b0,b2); swap(X1,X3) -> (b1,b3)
//   => lane half 0 holds kslots 0-7, half 1 holds kslots 8-15.  B[k][q] = P^T.
__device__ __forceinline__ f32x16 pv_tile(const f32x16 s, const bf16x8 vf0,
                                          const bf16x8 vf1, f32x16 acc) {
#pragma unroll
  for (int g = 0; g < 2; ++g) {
    unsigned X0 = pk2bf(ex2(s[g * 8 + 0]), ex2(s[g * 8 + 1]));
    unsigned X1 = pk2bf(ex2(s[g * 8 + 2]), ex2(s[g * 8 + 3]));
    unsigned X2 = pk2bf(ex2(s[g * 8 + 4]), ex2(s[g * 8 + 5]));
    unsigned X3 = pk2bf(ex2(s[g * 8 + 6]), ex2(s[g * 8 + 7]));
    plswap(X0, X2);
    plswap(X1, X3);
    union { unsigned u[4]; bf16x8 v; } pB;
    pB.u[0] = X0; pB.u[1] = X1; pB.u[2] = X2; pB.u[3] = X3;
    __builtin_amdgcn_s_setprio(1);
    acc = __builtin_amdgcn_mfma_f32_32x32x16_bf16(g ? vf1 : vf0, pB.v, acc,
                                                  0, 0, 0);
    __builtin_amdgcn_s_setprio(0);
  }
  return acc;
}

// ---------------------------------------------------------------------------
// Fused attention, MFMA, no LDS. grid (16, 8, KS) x 256 (4 waves; wave = 64 q).
__global__ __launch_bounds__(256, 4) void attn_mfma(
    const ushort_t* __restrict__ Qp, const ushort_t* __restrict__ Kp,
    const ushort_t* __restrict__ Vt, float* __restrict__ o_part, int kps) {
  const int tid = threadIdx.x;
  const int lane = tid & 63;
  const int wave = tid >> 6;
  const int l31 = lane & 31;
  const int lhalf = lane >> 5;
  const int h = blockIdx.y;
  const int ks = blockIdx.z;
  const int qb = blockIdx.x * 256 + wave * 64;

  bf16x8 qfrag0 = *(const bf16x8*)(Qp + ((size_t)h * N_VOX + qb + l31) * 8);
  bf16x8 qfrag1 = *(const bf16x8*)(Qp + ((size_t)h * N_VOX + qb + 32 + l31) * 8);

  f32x16 zf, acc0, acc1;
#pragma unroll
  for (int i = 0; i < 16; ++i) { zf[i] = 0.f; acc0[i] = 0.f; acc1[i] = 0.f; }

  const ushort_t* KpH = Kp + (size_t)h * N_VOX * 8;
  const ushort_t* VtH = Vt + ((size_t)h * 32 + l31) * N_VOX;

  const int kbeg = ks * kps;
  for (int kk = 0; kk < kps; kk += 32) {
    const int kcur = kbeg + kk;
    // K A-frag: lanes<32 = K[key][d0-7]; lanes>=32 (kslots 8-15) = zero.
    bf16x8 kf = {};
    if (!lhalf) kf = *(const bf16x8*)(KpH + (size_t)(kcur + l31) * 8);

    // Vt A-frags for PV: lane row = d (l31), k = key_local (lhalf*8+j).
    const bf16x8 vf0 = *(const bf16x8*)(VtH + kcur + lhalf * 8);
    const bf16x8 vf1 = *(const bf16x8*)(VtH + kcur + 16 + lhalf * 8);

    __builtin_amdgcn_s_setprio(1);
    const f32x16 s0 = __builtin_amdgcn_mfma_f32_32x32x16_bf16(kf, qfrag0, zf, 0, 0, 0);
    __builtin_amdgcn_s_setprio(0);
    acc0 = pv_tile(s0, vf0, vf1, acc0);

    __builtin_amdgcn_s_setprio(1);
    const f32x16 s1 = __builtin_amdgcn_mfma_f32_32x32x16_bf16(kf, qfrag1, zf, 0, 0, 0);
    __builtin_amdgcn_s_setprio(0);
    acc1 = pv_tile(s1, vf0, vf1, acc1);
  }

  // Epilogue: D row = d 0-7 (regs 0-3 per half), row 8 = l; col (l31) = q.
  float* ob = o_part + ((size_t)(ks * NH + h) * 9) * N_VOX;
#pragma unroll
  for (int t = 0; t < 2; ++t) {
    const f32x16 a = t ? acc1 : acc0;
    const int qx = qb + t * 32 + l31;
#pragma unroll
    for (int r = 0; r < 4; ++r)
      ob[(size_t)(r + 4 * lhalf) * N_VOX + qx] = a[r];
    if (lhalf == 0) ob[(size_t)8 * N_VOX + qx] = a[4];  // row 8 = denom
  }
}

// ---------------------------------------------------------------------------
// Combine split-K partials: ocomb[c][n] = sum_o / sum_l.  grid 1024 x 256.
__global__ __launch_bounds__(256) void combine(
    const float* __restrict__ o_part, float* __restrict__ ocomb, int KS) {
  const int t = blockIdx.x * 256 + threadIdx.x;
  const int c = t >> 12, n = t & (N_VOX - 1);
  const int h = c >> 3, d = c & 7;
  float so = 0.f, sl = 0.f;
  for (int s = 0; s < KS; ++s) {
    const float* base = o_part + ((size_t)(s * NH + h) * 9) * N_VOX;
    so += base[d * N_VOX + n];
    sl += base[8 * N_VOX + n];
  }
  ocomb[(size_t)c * N_VOX + n] = so / sl;
}

// ---------------------------------------------------------------------------
// Output projection (fp32).  grid (8, 16) x 256.
__global__ __launch_bounds__(256) void out_proj(
    const float* __restrict__ ocomb, const float* __restrict__ ow,
    const float* __restrict__ obias, float* __restrict__ out) {
  const int og = blockIdx.x;
  const int n = blockIdx.y * 256 + threadIdx.x;
  float x[64];
#pragma unroll
  for (int c = 0; c < 64; ++c) x[c] = ocomb[c * N_VOX + n];
#pragma unroll
  for (int j = 0; j < 8; ++j) {
    const int o = og * 8 + j;
    float acc = obias[o];
#pragma unroll
    for (int c = 0; c < 64; ++c) acc = fmaf(x[c], ow[o * 64 + c], acc);
    out[o * N_VOX + n] = acc;
  }
}

// ---------------------------------------------------------------------------
extern "C" void kernel_launch(void* const* d_in, const int* in_sizes, int n_in,
                              void* d_out, int out_size, void* d_ws, size_t ws_size,
                              hipStream_t stream) {
  const float* dec = (const float*)d_in[0];
  const float* mae = (const float*)d_in[1];
  const float* qw = (const float*)d_in[2];
  const float* qb = (const float*)d_in[3];
  const float* kw = (const float*)d_in[4];
  const float* kb = (const float*)d_in[5];
  const float* vw = (const float*)d_in[6];
  const float* vb = (const float*)d_in[7];
  const float* ow = (const float*)d_in[8];
  const float* ob = (const float*)d_in[9];
  float* out = (float*)d_out;
  char* ws = (char*)d_ws;

  const size_t OFF_QP = 0;                       // 512 KB
  const size_t OFF_KP = 0x80000;                 // 512 KB
  const size_t OFF_VT = 0x101000;                // 2 MB
  const size_t OFF_OPART = 0x301000;

  // Largest split-K fitting the workspace (ws_size constant -> graph-safe).
  int KS = 8;
  while (KS > 1) {
    size_t need = OFF_OPART + (size_t)KS * NH * 9 * N_VOX * 4 + 64ull * N_VOX * 4;
    if (need <= ws_size) break;
    KS >>= 1;
  }
  const size_t OFF_OCOMB = OFF_OPART + (size_t)KS * NH * 9 * N_VOX * 4;

  ushort_t* Qp = (ushort_t*)(ws + OFF_QP);
  ushort_t* Kp = (ushort_t*)(ws + OFF_KP);
  ushort_t* Vt = (ushort_t*)(ws + OFF_VT);
  float* o_part = (float*)(ws + OFF_OPART);
  float* ocomb = (float*)(ws + OFF_OCOMB);

  qkv_pack<<<dim3(16, 16), 256, 0, stream>>>(dec, mae, qw, qb, kw, kb, vw, vb,
                                             Qp, Kp, Vt);
  attn_mfma<<<dim3(16, 8, KS), 256, 0, stream>>>(Qp, Kp, Vt, o_part,
                                                 N_VOX / KS);
  combine<<<1024, 256, 0, stream>>>(o_part, ocomb, KS);
  out_proj<<<dim3(8, 16), 256, 0, stream>>>(ocomb, ow, ob, out);
}